// Round 18
// baseline (426.799 us; speedup 1.0000x reference)
//
#include <hip/hip_runtime.h>
#include <hip/hip_bf16.h>
#include <math.h>

typedef __attribute__((ext_vector_type(8))) __bf16 bf16x8;
typedef __attribute__((ext_vector_type(4))) float f32x4;
typedef __attribute__((ext_vector_type(4))) int i32x4;

// ---- sort configuration ---------------------------------------------------
#define NBUCKET 512            // 8x8x8 regions of 16^3 cells
#define HB      256            // histogram blocks
// workspace layout (bytes)
#define WS_WP   0UL                    // packed weights     32 KB
#define WS_MAT  32768UL                // [HB][NBUCKET] u32  512 KB
#define WS_TOT  557056UL               // 512 u32
#define WS_REC  561152UL               // rec[N] 16 B        32 MB
#define WS_FULL 34115584UL

__device__ __forceinline__ int bucket_key(float x, float y, float z) {
    int ix = (int)(x * 127.0f); ix = ix < 0 ? 0 : (ix > 127 ? 127 : ix);
    int iy = (int)(y * 127.0f); iy = iy < 0 ? 0 : (iy > 127 ? 127 : iy);
    int iz = (int)(z * 127.0f); iz = iz < 0 ? 0 : (iz > 127 ? 127 : iz);
    return ((ix >> 4) << 6) | ((iy >> 4) << 3) | (iz >> 4);
}

// ---------------------------------------------------------------------------
// Dispatch 1: blocks 0-7 pack MLP weights into MFMA A-fragment layout;
// blocks 8..8+HB-1 build per-block LDS histograms.
//   frags 0-7: wd1 ident | 8-11: wd2 K-perm | 12-27: wc1 F-layout | 28-31: wc2
// K-perm row(kt,kg,j) = 32kt + 16(j>>2) + 4kg + (j&3): previous layer's
// D-layout is directly the next layer's B-fragment (zero cross-lane moves).
// ---------------------------------------------------------------------------
__global__ __launch_bounds__(256)
void pack_hist(const float* __restrict__ wd1,
               const float* __restrict__ wd2,
               const float* __restrict__ wc1,
               const float* __restrict__ wc2,
               __bf16* __restrict__ wp,
               const float* __restrict__ coords,
               unsigned int* __restrict__ mat,
               int ppb)
{
    __shared__ unsigned int lh[NBUCKET];
    if (blockIdx.x < 8) {
        int t = blockIdx.x * 256 + threadIdx.x;   // 0..2047
        int frag = t >> 6;
        int lane = t & 63;
        int kg = lane >> 4;
        int c  = lane & 15;
        for (int j = 0; j < 8; ++j) {
            float v;
            if (frag < 8) {
                int k = kg * 8 + j;
                v = wd1[k * 128 + frag * 16 + c];
            } else if (frag < 12) {
                int kt = frag - 8;
                int row = 32 * kt + 16 * (j >> 2) + 4 * kg + (j & 3);
                v = wd2[row * 16 + c];
            } else if (frag < 28) {
                int f = frag - 12;
                int f3 = f >> 1, kt3 = f & 1;
                int row;
                if (kt3 == 0) row = (j < 4) ? (4 * kg + j) : (16 + 4 * kg + (j - 4));
                else          row = 32 + 8 * kg + j;
                v = (row < 43) ? wc1[row * 128 + f3 * 16 + c] : 0.0f;
            } else {
                int kt = frag - 28;
                int row = 32 * kt + 16 * (j >> 2) + 4 * kg + (j & 3);
                v = (c < 3) ? wc2[row * 3 + c] : 0.0f;
            }
            wp[frag * 512 + lane * 8 + j] = (__bf16)v;
        }
    } else {
        int hb = blockIdx.x - 8;
        for (int i = threadIdx.x; i < NBUCKET; i += 256) lh[i] = 0u;
        __syncthreads();
        int base = hb * ppb;
        for (int k = threadIdx.x; k < ppb; k += 256) {
            size_t b = 3 * (size_t)(base + k);
            atomicAdd(&lh[bucket_key(coords[b], coords[b + 1], coords[b + 2])], 1u);
        }
        __syncthreads();
        unsigned int* row = mat + (size_t)hb * NBUCKET;
        for (int i = threadIdx.x; i < NBUCKET; i += 256) row[i] = lh[i];
    }
}

// ---------------------------------------------------------------------------
// Dispatch 2: per-bucket exclusive scan over HB blocks (in place) + totals.
// ---------------------------------------------------------------------------
__global__ __launch_bounds__(256) void col_scan(unsigned int* __restrict__ mat,
                                                unsigned int* __restrict__ total)
{
    int wid  = threadIdx.x >> 6;
    int lane = threadIdx.x & 63;
    int bkt  = blockIdx.x * 4 + wid;

    unsigned int v[4];
#pragma unroll
    for (int j = 0; j < 4; ++j)
        v[j] = mat[(size_t)(lane * 4 + j) * NBUCKET + bkt];
    unsigned int pre[4];
    unsigned int sum = 0;
#pragma unroll
    for (int j = 0; j < 4; ++j) { pre[j] = sum; sum += v[j]; }
    unsigned int inc = sum;
    for (int d = 1; d < 64; d <<= 1) {
        unsigned int u = __shfl_up(inc, d);
        if (lane >= d) inc += u;
    }
    unsigned int excl = inc - sum;
#pragma unroll
    for (int j = 0; j < 4; ++j)
        mat[(size_t)(lane * 4 + j) * NBUCKET + bkt] = excl + pre[j];
    if (lane == 63) total[bkt] = inc;
}

// ---------------------------------------------------------------------------
// Dispatch 3: scatter packed 16-B records (512-entry bucket-base scan inlined
// in each block's prologue). Record: {x,y,z u16 | dx,dy,dz u16 | idx}.
// ---------------------------------------------------------------------------
__device__ __forceinline__ unsigned int q16(float v01) {
    float v = v01 * 65535.0f + 0.5f;
    v = v < 0.0f ? 0.0f : (v > 65535.0f ? 65535.0f : v);
    return (unsigned int)v;
}

__global__ __launch_bounds__(256)
void scatter16(const float* __restrict__ coords,
               const float* __restrict__ rayd,
               const unsigned int* __restrict__ mat,
               const unsigned int* __restrict__ total,
               unsigned int* __restrict__ rec,
               int ppb)
{
    __shared__ unsigned int cur[NBUCKET];
    __shared__ unsigned int wt[4];
    {
        int t = threadIdx.x;
        unsigned int v0 = total[2 * t], v1 = total[2 * t + 1];
        unsigned int run = v0 + v1;
        unsigned int lane = t & 63;
        int wid = t >> 6;
        unsigned int inc = run;
        for (int d = 1; d < 64; d <<= 1) {
            unsigned int u = __shfl_up(inc, d);
            if (lane >= (unsigned)d) inc += u;
        }
        if (lane == 63) wt[wid] = inc;
        __syncthreads();
        unsigned int wbase = 0;
        for (int w = 0; w < wid; ++w) wbase += wt[w];
        unsigned int excl = wbase + inc - run;
        const unsigned int* row = mat + (size_t)blockIdx.x * NBUCKET;
        cur[2 * t]     = excl + row[2 * t];
        cur[2 * t + 1] = excl + v0 + row[2 * t + 1];
    }
    __syncthreads();
    int base = blockIdx.x * ppb;
    for (int k = threadIdx.x; k < ppb; k += 256) {
        int i = base + k;
        size_t b = 3 * (size_t)i;
        float x = coords[b], y = coords[b + 1], z = coords[b + 2];
        unsigned int dst = atomicAdd(&cur[bucket_key(x, y, z)], 1u);
        unsigned int ux = q16(x), uy = q16(y), uz = q16(z);
        unsigned int vx = q16(fmaf(rayd[b],     0.5f, 0.5f));
        unsigned int vy = q16(fmaf(rayd[b + 1], 0.5f, 0.5f));
        unsigned int vz = q16(fmaf(rayd[b + 2], 0.5f, 0.5f));
        i32x4 r;
        r.x = (int)(ux | (uy << 16));
        r.y = (int)(uz | (vx << 16));
        r.z = (int)(vy | (vz << 16));
        r.w = i;
        ((i32x4*)rec)[dst] = r;
    }
}

__device__ __forceinline__ unsigned int pack2(float a, float b) {
    union { __bf16 h[2]; unsigned int u; } x;
    x.h[0] = (__bf16)a; x.h[1] = (__bf16)b;
    return x.u;
}

union BFU { bf16x8 v; unsigned int u[4]; };

// shared MLP body (L1->L4 given b0 frag + dirs dxv/dyv/dzv), LDSW = weight base
#define NERF_MLP_BODY(LDSW)                                                     \
    float s1x = __sinf(dxv), c1x = __cosf(dxv);                                 \
    float s1y = __sinf(dyv), c1y = __cosf(dyv);                                 \
    float s1z = __sinf(dzv), c1z = __cosf(dzv);                                 \
    float s2x = 2.0f * s1x * c1x, c2x = fmaf(-2.0f * s1x, s1x, 1.0f);           \
    float s2y = 2.0f * s1y * c1y, c2y = fmaf(-2.0f * s1y, s1y, 1.0f);           \
    float s2z = 2.0f * s1z * c1z, c2z = fmaf(-2.0f * s1z, s1z, 1.0f);           \
    float s4x = 2.0f * s2x * c2x, c4x = fmaf(-2.0f * s2x, s2x, 1.0f);           \
    float s4y = 2.0f * s2y * c2y, c4y = fmaf(-2.0f * s2y, s2y, 1.0f);           \
    float s4z = 2.0f * s2z * c2z, c4z = fmaf(-2.0f * s2z, s2z, 1.0f);           \
    float s8x = 2.0f * s4x * c4x, c8x = fmaf(-2.0f * s4x, s4x, 1.0f);           \
    float s8y = 2.0f * s4y * c4y, c8y = fmaf(-2.0f * s4y, s4y, 1.0f);           \
    float s8z = 2.0f * s4z * c4z, c8z = fmaf(-2.0f * s4z, s4z, 1.0f);           \
    float E0, E1, E2, E3, G0, G1, G2, G3, G4, G5, G6, G7;                       \
    if (kg == 0) {                                                              \
        E0 = dxv; E1 = dyv; E2 = dzv; E3 = s1x;                                 \
        G0 = c1y; G1 = c1z; G2 = c2x; G3 = c2y;                                 \
        G4 = c2z; G5 = c4x; G6 = c4y; G7 = c4z;                                 \
    } else if (kg == 1) {                                                       \
        E0 = s1y; E1 = s1z; E2 = s2x; E3 = s2y;                                 \
        G0 = c8x; G1 = c8y; G2 = c8z;                                           \
        G3 = 0.0f; G4 = 0.0f; G5 = 0.0f; G6 = 0.0f; G7 = 0.0f;                  \
    } else if (kg == 2) {                                                       \
        E0 = s2z; E1 = s4x; E2 = s4y; E3 = s4z;                                 \
        G0 = G1 = G2 = G3 = G4 = G5 = G6 = G7 = 0.0f;                           \
    } else {                                                                    \
        E0 = s8x; E1 = s8y; E2 = s8z; E3 = c1x;                                 \
        G0 = G1 = G2 = G3 = G4 = G5 = G6 = G7 = 0.0f;                           \
    }                                                                           \
    f32x4 acc[8];                                                               \
    _Pragma("unroll")                                                           \
    for (int n = 0; n < 8; ++n) {                                               \
        f32x4 bi = *(const f32x4*)(ldsB1 + n * 16 + kg * 4);                    \
        bf16x8 A = *(const bf16x8*)(LDSW + n * 1024 + lb);                      \
        acc[n] = __builtin_amdgcn_mfma_f32_16x16x32_bf16(A, b0.v, bi, 0, 0, 0); \
    }                                                                           \
    unsigned int pk[8][2];                                                      \
    _Pragma("unroll")                                                           \
    for (int n = 0; n < 8; ++n) {                                               \
        pk[n][0] = pack2(fmaxf(acc[n][0], 0.0f), fmaxf(acc[n][1], 0.0f));       \
        pk[n][1] = pack2(fmaxf(acc[n][2], 0.0f), fmaxf(acc[n][3], 0.0f));       \
    }                                                                           \
    f32x4 a2A = *(const f32x4*)(ldsB2 + kg * 4);                                \
    f32x4 a2B = {0.0f, 0.0f, 0.0f, 0.0f};                                       \
    _Pragma("unroll")                                                           \
    for (int kt = 0; kt < 4; ++kt) {                                            \
        BFU B;                                                                  \
        B.u[0] = pk[2 * kt][0];     B.u[1] = pk[2 * kt][1];                     \
        B.u[2] = pk[2 * kt + 1][0]; B.u[3] = pk[2 * kt + 1][1];                 \
        bf16x8 A = *(const bf16x8*)(LDSW + (8 + kt) * 1024 + lb);               \
        if (kt & 1) a2B = __builtin_amdgcn_mfma_f32_16x16x32_bf16(A, B.v, a2B, 0, 0, 0); \
        else        a2A = __builtin_amdgcn_mfma_f32_16x16x32_bf16(A, B.v, a2A, 0, 0, 0); \
    }                                                                           \
    f32x4 accd = a2A + a2B;                                                     \
    float dens = fmaxf(accd[0], 0.0f);                                          \
    BFU Bk0, Bk1;                                                               \
    Bk0.u[0] = pack2(accd[0], accd[1]);                                         \
    Bk0.u[1] = pack2(accd[2], accd[3]);                                         \
    Bk0.u[2] = pack2(E0, E1);                                                   \
    Bk0.u[3] = pack2(E2, E3);                                                   \
    Bk1.u[0] = pack2(G0, G1);                                                   \
    Bk1.u[1] = pack2(G2, G3);                                                   \
    Bk1.u[2] = pack2(G4, G5);                                                   \
    Bk1.u[3] = pack2(G6, G7);                                                   \
    f32x4 acc3[8];                                                              \
    _Pragma("unroll")                                                           \
    for (int n = 0; n < 8; ++n) {                                               \
        f32x4 bi = *(const f32x4*)(ldsB3 + n * 16 + kg * 4);                    \
        bf16x8 w0 = *(const bf16x8*)(LDSW + (12 + n * 2 + 0) * 1024 + lb);      \
        bf16x8 w1 = *(const bf16x8*)(LDSW + (12 + n * 2 + 1) * 1024 + lb);      \
        acc3[n] = __builtin_amdgcn_mfma_f32_16x16x32_bf16(w0, Bk0.v, bi, 0, 0, 0);      \
        acc3[n] = __builtin_amdgcn_mfma_f32_16x16x32_bf16(w1, Bk1.v, acc3[n], 0, 0, 0); \
    }                                                                           \
    unsigned int pk3[8][2];                                                     \
    _Pragma("unroll")                                                           \
    for (int n = 0; n < 8; ++n) {                                               \
        pk3[n][0] = pack2(fmaxf(acc3[n][0], 0.0f), fmaxf(acc3[n][1], 0.0f));    \
        pk3[n][1] = pack2(fmaxf(acc3[n][2], 0.0f), fmaxf(acc3[n][3], 0.0f));    \
    }                                                                           \
    f32x4 a4A = *(const f32x4*)(ldsB4 + kg * 4);                                \
    f32x4 a4B = {0.0f, 0.0f, 0.0f, 0.0f};                                       \
    _Pragma("unroll")                                                           \
    for (int kt = 0; kt < 4; ++kt) {                                            \
        BFU B;                                                                  \
        B.u[0] = pk3[2 * kt][0];     B.u[1] = pk3[2 * kt][1];                   \
        B.u[2] = pk3[2 * kt + 1][0]; B.u[3] = pk3[2 * kt + 1][1];               \
        bf16x8 A = *(const bf16x8*)(LDSW + (28 + kt) * 1024 + lb);              \
        if (kt & 1) a4B = __builtin_amdgcn_mfma_f32_16x16x32_bf16(A, B.v, a4B, 0, 0, 0); \
        else        a4A = __builtin_amdgcn_mfma_f32_16x16x32_bf16(A, B.v, a4A, 0, 0, 0); \
    }                                                                           \
    f32x4 acco = a4A + a4B;

// consume one fp32 corner (two f32x4 halves) into fa/fb
#define CONSUME32(GA, GB, W) {                                                  \
    float w_ = (W);                                                             \
    fa[0] = fmaf(w_, (GA)[0], fa[0]); fa[1] = fmaf(w_, (GA)[1], fa[1]);         \
    fa[2] = fmaf(w_, (GA)[2], fa[2]); fa[3] = fmaf(w_, (GA)[3], fa[3]);         \
    fb[0] = fmaf(w_, (GB)[0], fb[0]); fb[1] = fmaf(w_, (GB)[1], fb[1]);         \
    fb[2] = fmaf(w_, (GB)[2], fb[2]); fb[3] = fmaf(w_, (GB)[3], fb[3]);         \
}

// issue the 16 corner loads for a decoded point (fp32 grid)
#define ISSUE_CORNERS(GP)                                                       \
    gA0 = *(const f32x4*)((GP));           gB0 = *(const f32x4*)((GP) + 4);     \
    gA1 = *(const f32x4*)((GP) + 32);      gB1 = *(const f32x4*)((GP) + 36);    \
    gA2 = *(const f32x4*)((GP) + 4096);    gB2 = *(const f32x4*)((GP) + 4100);  \
    gA3 = *(const f32x4*)((GP) + 4128);    gB3 = *(const f32x4*)((GP) + 4132);  \
    gA4 = *(const f32x4*)((GP) + 524288);  gB4 = *(const f32x4*)((GP) + 524292);\
    gA5 = *(const f32x4*)((GP) + 524320);  gB5 = *(const f32x4*)((GP) + 524324);\
    gA6 = *(const f32x4*)((GP) + 528384);  gB6 = *(const f32x4*)((GP) + 528388);\
    gA7 = *(const f32x4*)((GP) + 528416);  gB7 = *(const f32x4*)((GP) + 528420);

// ---------------------------------------------------------------------------
// Dispatch 4: pipelined main kernel, fp32 grid direct (no conversion pass).
// Iteration t consumes the 16 corner halves loaded during t-1, issues t+1's
// loads, then runs the MLP while they fly. Lane-local 16-B record decode.
// ---------------------------------------------------------------------------
__global__ __launch_bounds__(512)
void nerf_pipe32(const float* __restrict__ grid,
                 const unsigned int* __restrict__ rec,
                 const float* __restrict__ bd1,
                 const float* __restrict__ bd2,
                 const float* __restrict__ bc1,
                 const float* __restrict__ bc2,
                 const __bf16* __restrict__ wp,
                 float* __restrict__ out,
                 int ntiles)                        // 128-point tiles
{
    __shared__ __align__(16) char lds[32768 + 1152];
    float* ldsB1 = (float*)(lds + 32768);
    float* ldsB2 = ldsB1 + 128;
    float* ldsB3 = ldsB2 + 16;
    float* ldsB4 = ldsB3 + 128;

    const int tid = threadIdx.x;
    {
        const i32x4* src = (const i32x4*)wp;
        i32x4* dst = (i32x4*)lds;
        for (int i = tid; i < 2048; i += 512) dst[i] = src[i];
        if (tid < 128) ldsB1[tid] = bd1[tid];
        if (tid < 16)  ldsB2[tid] = bd2[tid];
        if (tid < 128) ldsB3[tid] = bc1[tid];
        if (tid < 16)  ldsB4[tid] = (tid < 3) ? bc2[tid] : 0.0f;
    }
    __syncthreads();

    const int lane = tid & 63;
    const int wid  = tid >> 6;
    const int c    = lane & 15;
    const int kg   = lane >> 4;
    const int lb   = lane * 16;

    const int per = (ntiles + gridDim.x - 1) / gridDim.x;
    int sb = blockIdx.x;
    if ((gridDim.x & 7) == 0)
        sb = (blockIdx.x & 7) * (gridDim.x >> 3) + (blockIdx.x >> 3);

    // ---- prologue ----------------------------------------------------------
    int t0 = sb * per;       if (t0 >= ntiles) t0 = ntiles - 1;
    int t1 = sb * per + 1;   if (t1 >= ntiles) t1 = ntiles - 1;
    i32x4 recA = ((const i32x4*)rec)[(size_t)t0 * 128 + wid * 16 + c];
    i32x4 recB = ((const i32x4*)rec)[(size_t)t1 * 128 + wid * 16 + c];

    f32x4 gA0, gA1, gA2, gA3, gA4, gA5, gA6, gA7;
    f32x4 gB0, gB1, gB2, gB3, gB4, gB5, gB6, gB7;
    float txc, tyc, tzc;
    {   // prep iter 0 from recA
        float px = (float)((unsigned)recA.x & 0xffffu) * (127.0f / 65535.0f);
        float py = (float)((unsigned)recA.x >> 16)     * (127.0f / 65535.0f);
        float pz = (float)((unsigned)recA.y & 0xffffu) * (127.0f / 65535.0f);
        int ix = (int)floorf(px); ix = ix < 0 ? 0 : (ix > 126 ? 126 : ix);
        int iy = (int)floorf(py); iy = iy < 0 ? 0 : (iy > 126 ? 126 : iy);
        int iz = (int)floorf(pz); iz = iz < 0 ? 0 : (iz > 126 ? 126 : iz);
        txc = px - (float)ix; tyc = py - (float)iy; tzc = pz - (float)iz;
        const float* gp = grid + ((((size_t)ix << 14) + ((size_t)iy << 7) + iz) * 32 + kg * 8);
        ISSUE_CORNERS(gp)
    }

    for (int it = 0; it < per; ++it) {
        const int tile = sb * per + it;
        if (tile >= ntiles) break;

        // ---- consume current corner halves -> b0 frag ----------------------
        f32x4 fa = {0.0f, 0.0f, 0.0f, 0.0f};
        f32x4 fb = {0.0f, 0.0f, 0.0f, 0.0f};
        {
            float wx1 = txc, wx0 = 1.0f - txc;
            float wy1 = tyc, wy0 = 1.0f - tyc;
            float wz1 = tzc, wz0 = 1.0f - tzc;
            float wA = wx0 * wy0, wB = wx0 * wy1;
            float wC = wx1 * wy0, wD = wx1 * wy1;
            CONSUME32(gA0, gB0, wA * wz0)   // (0,0,0)
            CONSUME32(gA1, gB1, wA * wz1)   // (0,0,1)
            CONSUME32(gA2, gB2, wB * wz0)   // (0,1,0)
            CONSUME32(gA3, gB3, wB * wz1)   // (0,1,1)
            CONSUME32(gA4, gB4, wC * wz0)   // (1,0,0)
            CONSUME32(gA5, gB5, wC * wz1)   // (1,0,1)
            CONSUME32(gA6, gB6, wD * wz0)   // (1,1,0)
            CONSUME32(gA7, gB7, wD * wz1)   // (1,1,1)
        }
        BFU b0;
        b0.u[0] = pack2(fa[0], fa[1]); b0.u[1] = pack2(fa[2], fa[3]);
        b0.u[2] = pack2(fb[0], fb[1]); b0.u[3] = pack2(fb[2], fb[3]);

        // ---- current dirs / output index (lane-local decode) ---------------
        float dxv = fmaf((float)((unsigned)recA.y >> 16),     2.0f / 65535.0f, -1.0f);
        float dyv = fmaf((float)((unsigned)recA.z & 0xffffu), 2.0f / 65535.0f, -1.0f);
        float dzv = fmaf((float)((unsigned)recA.z >> 16),     2.0f / 65535.0f, -1.0f);
        int   pv  = recA.w;

        // ---- prep NEXT iteration from recB: issue 16 corner loads ----------
        {
            float px = (float)((unsigned)recB.x & 0xffffu) * (127.0f / 65535.0f);
            float py = (float)((unsigned)recB.x >> 16)     * (127.0f / 65535.0f);
            float pz = (float)((unsigned)recB.y & 0xffffu) * (127.0f / 65535.0f);
            int ix = (int)floorf(px); ix = ix < 0 ? 0 : (ix > 126 ? 126 : ix);
            int iy = (int)floorf(py); iy = iy < 0 ? 0 : (iy > 126 ? 126 : iy);
            int iz = (int)floorf(pz); iz = iz < 0 ? 0 : (iz > 126 ? 126 : iz);
            txc = px - (float)ix; tyc = py - (float)iy; tzc = pz - (float)iz;
            const float* gp = grid + ((((size_t)ix << 14) + ((size_t)iy << 7) + iz) * 32 + kg * 8);
            ISSUE_CORNERS(gp)
        }
        // rotate records: recA <- recB, load new recB (t+2)
        recA = recB;
        {
            int t2 = tile + 2; if (t2 >= ntiles) t2 = ntiles - 1;
            recB = ((const i32x4*)rec)[(size_t)t2 * 128 + wid * 16 + c];
        }

        // ---- MLP (corner loads above retire underneath) --------------------
        NERF_MLP_BODY(lds + 0)

        if (lane < 16) {
            f32x4 o;
            o[0] = 1.0f / (1.0f + __expf(-acco[0]));
            o[1] = 1.0f / (1.0f + __expf(-acco[1]));
            o[2] = 1.0f / (1.0f + __expf(-acco[2]));
            o[3] = dens;
            ((f32x4*)out)[pv] = o;
        }
    }
}

// ---------------------------------------------------------------------------
// Fallback (no workspace): unsorted fp32-gather kernel.
// ---------------------------------------------------------------------------
__global__ void pack_weights_fb(const float* __restrict__ wd1,
                                const float* __restrict__ wd2,
                                const float* __restrict__ wc1,
                                const float* __restrict__ wc2,
                                __bf16* __restrict__ wp)
{
    int t = blockIdx.x * 256 + threadIdx.x;
    int frag = t >> 6;
    int lane = t & 63;
    int kg = lane >> 4;
    int c  = lane & 15;
    for (int j = 0; j < 8; ++j) {
        float v;
        if (frag < 8) {
            int k = kg * 8 + j;
            v = wd1[k * 128 + frag * 16 + c];
        } else if (frag < 12) {
            int kt = frag - 8;
            int row = 32 * kt + 16 * (j >> 2) + 4 * kg + (j & 3);
            v = wd2[row * 16 + c];
        } else if (frag < 28) {
            int f = frag - 12;
            int f3 = f >> 1, kt3 = f & 1;
            int row;
            if (kt3 == 0) row = (j < 4) ? (4 * kg + j) : (16 + 4 * kg + (j - 4));
            else          row = 32 + 8 * kg + j;
            v = (row < 43) ? wc1[row * 128 + f3 * 16 + c] : 0.0f;
        } else {
            int kt = frag - 28;
            int row = 32 * kt + 16 * (j >> 2) + 4 * kg + (j & 3);
            v = (c < 3) ? wc2[row * 3 + c] : 0.0f;
        }
        wp[frag * 512 + lane * 8 + j] = (__bf16)v;
    }
}

__global__ __launch_bounds__(512)
void nerf_plain(const float* __restrict__ coords,
                const float* __restrict__ ray_d,
                const float* __restrict__ grid,
                const float* __restrict__ bd1,
                const float* __restrict__ bd2,
                const float* __restrict__ bc1,
                const float* __restrict__ bc2,
                const __bf16* __restrict__ wp,
                float* __restrict__ out,
                int ntiles)
{
    __shared__ __align__(16) char lds[32768 + 1152];
    float* ldsB1 = (float*)(lds + 32768);
    float* ldsB2 = ldsB1 + 128;
    float* ldsB3 = ldsB2 + 16;
    float* ldsB4 = ldsB3 + 128;

    const int tid = threadIdx.x;
    {
        const i32x4* src = (const i32x4*)wp;
        i32x4* dst = (i32x4*)lds;
        for (int i = tid; i < 2048; i += 512) dst[i] = src[i];
        if (tid < 128) ldsB1[tid] = bd1[tid];
        if (tid < 16)  ldsB2[tid] = bd2[tid];
        if (tid < 128) ldsB3[tid] = bc1[tid];
        if (tid < 16)  ldsB4[tid] = (tid < 3) ? bc2[tid] : 0.0f;
    }
    __syncthreads();

    const int lane = tid & 63;
    const int wid  = tid >> 6;
    const int c    = lane & 15;
    const int kg   = lane >> 4;
    const int lb   = lane * 16;

    for (int tile = blockIdx.x; tile < ntiles; tile += gridDim.x) {
        int pw = tile * 128 + wid * 16;
        float cval = (lane < 48) ? coords[(size_t)pw * 3 + lane] : 0.0f;
        float rval = (lane < 48) ? ray_d[(size_t)pw * 3 + lane] : 0.0f;
        float px  = __shfl(cval, 3 * c + 0) * 127.0f;
        float py  = __shfl(cval, 3 * c + 1) * 127.0f;
        float pz  = __shfl(cval, 3 * c + 2) * 127.0f;
        float dxv = __shfl(rval, 3 * c + 0);
        float dyv = __shfl(rval, 3 * c + 1);
        float dzv = __shfl(rval, 3 * c + 2);
        int pv = pw + c;

        int ix = (int)floorf(px); ix = ix < 0 ? 0 : (ix > 126 ? 126 : ix);
        int iy = (int)floorf(py); iy = iy < 0 ? 0 : (iy > 126 ? 126 : iy);
        int iz = (int)floorf(pz); iz = iz < 0 ? 0 : (iz > 126 ? 126 : iz);
        float tx = px - (float)ix;
        float ty = py - (float)iy;
        float tz = pz - (float)iz;

        f32x4 fa = {0.0f, 0.0f, 0.0f, 0.0f};
        f32x4 fb = {0.0f, 0.0f, 0.0f, 0.0f};
#pragma unroll
        for (int cc = 0; cc < 8; ++cc) {
            int ddx = (cc >> 2) & 1, ddy = (cc >> 1) & 1, ddz = cc & 1;
            float w = (ddx ? tx : 1.0f - tx) *
                      (ddy ? ty : 1.0f - ty) *
                      (ddz ? tz : 1.0f - tz);
            int idx = ((ix + ddx) << 14) + ((iy + ddy) << 7) + (iz + ddz);
            const f32x4* g = (const f32x4*)(grid + (size_t)idx * 32 + kg * 8);
            f32x4 v0 = g[0], v1 = g[1];
#pragma unroll
            for (int e = 0; e < 4; ++e) {
                fa[e] = fmaf(w, v0[e], fa[e]);
                fb[e] = fmaf(w, v1[e], fb[e]);
            }
        }
        BFU b0;
        b0.u[0] = pack2(fa[0], fa[1]); b0.u[1] = pack2(fa[2], fa[3]);
        b0.u[2] = pack2(fb[0], fb[1]); b0.u[3] = pack2(fb[2], fb[3]);

        NERF_MLP_BODY(lds + 0)

        if (lane < 16) {
            f32x4 o;
            o[0] = 1.0f / (1.0f + __expf(-acco[0]));
            o[1] = 1.0f / (1.0f + __expf(-acco[1]));
            o[2] = 1.0f / (1.0f + __expf(-acco[2]));
            o[3] = dens;
            ((f32x4*)out)[pv] = o;
        }
    }
}

extern "C" void kernel_launch(void* const* d_in, const int* in_sizes, int n_in,
                              void* d_out, int out_size, void* d_ws, size_t ws_size,
                              hipStream_t stream) {
    const float* coords = (const float*)d_in[0];
    const float* ray_d  = (const float*)d_in[1];
    const float* grid   = (const float*)d_in[2];
    const float* wd1    = (const float*)d_in[3];
    const float* bd1    = (const float*)d_in[4];
    const float* wd2    = (const float*)d_in[5];
    const float* bd2    = (const float*)d_in[6];
    const float* wc1    = (const float*)d_in[7];
    const float* bc1    = (const float*)d_in[8];
    const float* wc2    = (const float*)d_in[9];
    const float* bc2    = (const float*)d_in[10];
    float* out = (float*)d_out;

    int N = in_sizes[0] / 3;
    int ntiles = N >> 7;

    char* ws = (char*)d_ws;
    __bf16* wp = (__bf16*)(ws + WS_WP);

    bool sortable = (N % (HB * 128)) == 0;

    if (ws_size >= WS_FULL && sortable) {
        unsigned int* mat   = (unsigned int*)(ws + WS_MAT);
        unsigned int* total = (unsigned int*)(ws + WS_TOT);
        unsigned int* rec   = (unsigned int*)(ws + WS_REC);
        int ppb = N / HB;

        pack_hist<<<8 + HB, 256, 0, stream>>>(wd1, wd2, wc1, wc2, wp,
                                              coords, mat, ppb);
        col_scan<<<NBUCKET / 4, 256, 0, stream>>>(mat, total);
        scatter16<<<HB, 256, 0, stream>>>(coords, ray_d, mat, total, rec, ppb);
        int blocks = ntiles < 2048 ? ntiles : 2048;
        nerf_pipe32<<<blocks, 512, 0, stream>>>(grid, rec,
                                                bd1, bd2, bc1, bc2, wp, out, ntiles);
    } else {
        pack_weights_fb<<<8, 256, 0, stream>>>(wd1, wd2, wc1, wc2, wp);
        int blocks = ntiles < 2048 ? ntiles : 2048;
        nerf_plain<<<blocks, 512, 0, stream>>>(coords, ray_d, grid,
                                               bd1, bd2, bc1, bc2,
                                               wp, out, ntiles);
    }
}

// Round 19
// 333.996 us; speedup vs baseline: 1.2779x; 1.2779x over previous
//
#include <hip/hip_runtime.h>
#include <hip/hip_bf16.h>
#include <math.h>

typedef __attribute__((ext_vector_type(8))) __bf16 bf16x8;
typedef __attribute__((ext_vector_type(4))) float f32x4;
typedef __attribute__((ext_vector_type(4))) int i32x4;

// ---- sort configuration ---------------------------------------------------
#define NBUCKET 512            // 8x8x8 regions of 16^3 cells
#define HB      256            // histogram blocks
// workspace layout (bytes)
#define WS_WP   0UL                    // packed weights     32 KB
#define WS_MAT  32768UL                // [HB][NBUCKET] u32  512 KB
#define WS_TOT  557056UL               // 512 u32
#define WS_REC  561152UL               // rec[N] 16 B        32 MB
#define WS_GB   34115584UL             // bf16 grid          134 MB
#define WS_FULL 168333312UL

__device__ __forceinline__ int bucket_key(float x, float y, float z) {
    int ix = (int)(x * 127.0f); ix = ix < 0 ? 0 : (ix > 127 ? 127 : ix);
    int iy = (int)(y * 127.0f); iy = iy < 0 ? 0 : (iy > 127 ? 127 : iy);
    int iz = (int)(z * 127.0f); iz = iz < 0 ? 0 : (iz > 127 ? 127 : iz);
    return ((ix >> 4) << 6) | ((iy >> 4) << 3) | (iz >> 4);
}

// ---------------------------------------------------------------------------
// Dispatch 1: blocks 0-7 pack MLP weights into MFMA A-fragment layout;
// blocks 8..8+HB-1 build per-block LDS histograms.
//   frags 0-7: wd1 ident | 8-11: wd2 K-perm | 12-27: wc1 F-layout | 28-31: wc2
// K-perm row(kt,kg,j) = 32kt + 16(j>>2) + 4kg + (j&3): previous layer's
// D-layout is directly the next layer's B-fragment (zero cross-lane moves).
// ---------------------------------------------------------------------------
__global__ __launch_bounds__(256)
void pack_hist(const float* __restrict__ wd1,
               const float* __restrict__ wd2,
               const float* __restrict__ wc1,
               const float* __restrict__ wc2,
               __bf16* __restrict__ wp,
               const float* __restrict__ coords,
               unsigned int* __restrict__ mat,
               int ppb)
{
    __shared__ unsigned int lh[NBUCKET];
    if (blockIdx.x < 8) {
        int t = blockIdx.x * 256 + threadIdx.x;   // 0..2047
        int frag = t >> 6;
        int lane = t & 63;
        int kg = lane >> 4;
        int c  = lane & 15;
        for (int j = 0; j < 8; ++j) {
            float v;
            if (frag < 8) {
                int k = kg * 8 + j;
                v = wd1[k * 128 + frag * 16 + c];
            } else if (frag < 12) {
                int kt = frag - 8;
                int row = 32 * kt + 16 * (j >> 2) + 4 * kg + (j & 3);
                v = wd2[row * 16 + c];
            } else if (frag < 28) {
                int f = frag - 12;
                int f3 = f >> 1, kt3 = f & 1;
                int row;
                if (kt3 == 0) row = (j < 4) ? (4 * kg + j) : (16 + 4 * kg + (j - 4));
                else          row = 32 + 8 * kg + j;
                v = (row < 43) ? wc1[row * 128 + f3 * 16 + c] : 0.0f;
            } else {
                int kt = frag - 28;
                int row = 32 * kt + 16 * (j >> 2) + 4 * kg + (j & 3);
                v = (c < 3) ? wc2[row * 3 + c] : 0.0f;
            }
            wp[frag * 512 + lane * 8 + j] = (__bf16)v;
        }
    } else {
        int hb = blockIdx.x - 8;
        for (int i = threadIdx.x; i < NBUCKET; i += 256) lh[i] = 0u;
        __syncthreads();
        int base = hb * ppb;
        for (int k = threadIdx.x; k < ppb; k += 256) {
            size_t b = 3 * (size_t)(base + k);
            atomicAdd(&lh[bucket_key(coords[b], coords[b + 1], coords[b + 2])], 1u);
        }
        __syncthreads();
        unsigned int* row = mat + (size_t)hb * NBUCKET;
        for (int i = threadIdx.x; i < NBUCKET; i += 256) row[i] = lh[i];
    }
}

// ---------------------------------------------------------------------------
// Dispatch 2: per-bucket exclusive scan over HB blocks (in place) + totals.
// ---------------------------------------------------------------------------
__global__ __launch_bounds__(256) void col_scan(unsigned int* __restrict__ mat,
                                                unsigned int* __restrict__ total)
{
    int wid  = threadIdx.x >> 6;
    int lane = threadIdx.x & 63;
    int bkt  = blockIdx.x * 4 + wid;

    unsigned int v[4];
#pragma unroll
    for (int j = 0; j < 4; ++j)
        v[j] = mat[(size_t)(lane * 4 + j) * NBUCKET + bkt];
    unsigned int pre[4];
    unsigned int sum = 0;
#pragma unroll
    for (int j = 0; j < 4; ++j) { pre[j] = sum; sum += v[j]; }
    unsigned int inc = sum;
    for (int d = 1; d < 64; d <<= 1) {
        unsigned int u = __shfl_up(inc, d);
        if (lane >= d) inc += u;
    }
    unsigned int excl = inc - sum;
#pragma unroll
    for (int j = 0; j < 4; ++j)
        mat[(size_t)(lane * 4 + j) * NBUCKET + bkt] = excl + pre[j];
    if (lane == 63) total[bkt] = inc;
}

// ---------------------------------------------------------------------------
// Dispatch 3: blocks 0..HB-1 scatter packed 16-B records (with the 512-entry
// bucket-base scan inlined in the prologue); blocks >= HB convert the fp32
// grid to bf16 (overlaps the scatter on the memory pipe).
// Record: {x,y,z u16 | dx,dy,dz u16 | idx}. Coord quant err 7.6e-6.
// ---------------------------------------------------------------------------
__device__ __forceinline__ unsigned int q16(float v01) {
    float v = v01 * 65535.0f + 0.5f;
    v = v < 0.0f ? 0.0f : (v > 65535.0f ? 65535.0f : v);
    return (unsigned int)v;
}

__global__ __launch_bounds__(256)
void scatter_conv(const float* __restrict__ coords,
                  const float* __restrict__ rayd,
                  const unsigned int* __restrict__ mat,
                  const unsigned int* __restrict__ total,
                  unsigned int* __restrict__ rec,
                  int ppb,
                  const float* __restrict__ g,
                  __bf16* __restrict__ gb,
                  int n8)
{
    __shared__ unsigned int cur[NBUCKET];
    __shared__ unsigned int wt[4];
    if (blockIdx.x >= HB) {
        // ---- grid conversion ----
        int i0 = (blockIdx.x - HB) * 256 + threadIdx.x;
        int stride = (gridDim.x - HB) * 256;
        for (int i = i0; i < n8; i += stride) {
            const f32x4* p = (const f32x4*)g + 2 * (size_t)i;
            f32x4 a = p[0], b = p[1];
            bf16x8 o;
#pragma unroll
            for (int e = 0; e < 4; ++e) {
                o[e]     = (__bf16)a[e];
                o[4 + e] = (__bf16)b[e];
            }
            ((bf16x8*)gb)[i] = o;
        }
        return;
    }
    // ---- inline bucket-base scan (each block redundantly) ----
    {
        int t = threadIdx.x;
        unsigned int v0 = total[2 * t], v1 = total[2 * t + 1];
        unsigned int run = v0 + v1;
        unsigned int lane = t & 63;
        int wid = t >> 6;
        unsigned int inc = run;
        for (int d = 1; d < 64; d <<= 1) {
            unsigned int u = __shfl_up(inc, d);
            if (lane >= (unsigned)d) inc += u;
        }
        if (lane == 63) wt[wid] = inc;
        __syncthreads();
        unsigned int wbase = 0;
        for (int w = 0; w < wid; ++w) wbase += wt[w];
        unsigned int excl = wbase + inc - run;
        const unsigned int* row = mat + (size_t)blockIdx.x * NBUCKET;
        cur[2 * t]     = excl + row[2 * t];
        cur[2 * t + 1] = excl + v0 + row[2 * t + 1];
    }
    __syncthreads();
    int base = blockIdx.x * ppb;
    for (int k = threadIdx.x; k < ppb; k += 256) {
        int i = base + k;
        size_t b = 3 * (size_t)i;
        float x = coords[b], y = coords[b + 1], z = coords[b + 2];
        unsigned int dst = atomicAdd(&cur[bucket_key(x, y, z)], 1u);
        unsigned int ux = q16(x), uy = q16(y), uz = q16(z);
        unsigned int vx = q16(fmaf(rayd[b],     0.5f, 0.5f));
        unsigned int vy = q16(fmaf(rayd[b + 1], 0.5f, 0.5f));
        unsigned int vz = q16(fmaf(rayd[b + 2], 0.5f, 0.5f));
        i32x4 r;
        r.x = (int)(ux | (uy << 16));
        r.y = (int)(uz | (vx << 16));
        r.z = (int)(vy | (vz << 16));
        r.w = i;
        ((i32x4*)rec)[dst] = r;
    }
}

__device__ __forceinline__ unsigned int pack2(float a, float b) {
    union { __bf16 h[2]; unsigned int u; } x;
    x.h[0] = (__bf16)a; x.h[1] = (__bf16)b;
    return x.u;
}

union BFU { bf16x8 v; unsigned int u[4]; };

// shared MLP body (L1->L4 given b0 frag + dirs dxv/dyv/dzv), LDSW = weight base
// s_setprio(1) wraps each MFMA cluster (waves are barrier-free & phase-diverse
// in the main loop -> T5 regime).
#define NERF_MLP_BODY(LDSW)                                                     \
    float s1x = __sinf(dxv), c1x = __cosf(dxv);                                 \
    float s1y = __sinf(dyv), c1y = __cosf(dyv);                                 \
    float s1z = __sinf(dzv), c1z = __cosf(dzv);                                 \
    float s2x = 2.0f * s1x * c1x, c2x = fmaf(-2.0f * s1x, s1x, 1.0f);           \
    float s2y = 2.0f * s1y * c1y, c2y = fmaf(-2.0f * s1y, s1y, 1.0f);           \
    float s2z = 2.0f * s1z * c1z, c2z = fmaf(-2.0f * s1z, s1z, 1.0f);           \
    float s4x = 2.0f * s2x * c2x, c4x = fmaf(-2.0f * s2x, s2x, 1.0f);           \
    float s4y = 2.0f * s2y * c2y, c4y = fmaf(-2.0f * s2y, s2y, 1.0f);           \
    float s4z = 2.0f * s2z * c2z, c4z = fmaf(-2.0f * s2z, s2z, 1.0f);           \
    float s8x = 2.0f * s4x * c4x, c8x = fmaf(-2.0f * s4x, s4x, 1.0f);           \
    float s8y = 2.0f * s4y * c4y, c8y = fmaf(-2.0f * s4y, s4y, 1.0f);           \
    float s8z = 2.0f * s4z * c4z, c8z = fmaf(-2.0f * s4z, s4z, 1.0f);           \
    float E0, E1, E2, E3, G0, G1, G2, G3, G4, G5, G6, G7;                       \
    if (kg == 0) {                                                              \
        E0 = dxv; E1 = dyv; E2 = dzv; E3 = s1x;                                 \
        G0 = c1y; G1 = c1z; G2 = c2x; G3 = c2y;                                 \
        G4 = c2z; G5 = c4x; G6 = c4y; G7 = c4z;                                 \
    } else if (kg == 1) {                                                       \
        E0 = s1y; E1 = s1z; E2 = s2x; E3 = s2y;                                 \
        G0 = c8x; G1 = c8y; G2 = c8z;                                           \
        G3 = 0.0f; G4 = 0.0f; G5 = 0.0f; G6 = 0.0f; G7 = 0.0f;                  \
    } else if (kg == 2) {                                                       \
        E0 = s2z; E1 = s4x; E2 = s4y; E3 = s4z;                                 \
        G0 = G1 = G2 = G3 = G4 = G5 = G6 = G7 = 0.0f;                           \
    } else {                                                                    \
        E0 = s8x; E1 = s8y; E2 = s8z; E3 = c1x;                                 \
        G0 = G1 = G2 = G3 = G4 = G5 = G6 = G7 = 0.0f;                           \
    }                                                                           \
    f32x4 acc[8];                                                               \
    __builtin_amdgcn_s_setprio(1);                                              \
    _Pragma("unroll")                                                           \
    for (int n = 0; n < 8; ++n) {                                               \
        f32x4 bi = *(const f32x4*)(ldsB1 + n * 16 + kg * 4);                    \
        bf16x8 A = *(const bf16x8*)(LDSW + n * 1024 + lb);                      \
        acc[n] = __builtin_amdgcn_mfma_f32_16x16x32_bf16(A, b0.v, bi, 0, 0, 0); \
    }                                                                           \
    __builtin_amdgcn_s_setprio(0);                                              \
    unsigned int pk[8][2];                                                      \
    _Pragma("unroll")                                                           \
    for (int n = 0; n < 8; ++n) {                                               \
        pk[n][0] = pack2(fmaxf(acc[n][0], 0.0f), fmaxf(acc[n][1], 0.0f));       \
        pk[n][1] = pack2(fmaxf(acc[n][2], 0.0f), fmaxf(acc[n][3], 0.0f));       \
    }                                                                           \
    f32x4 a2A = *(const f32x4*)(ldsB2 + kg * 4);                                \
    f32x4 a2B = {0.0f, 0.0f, 0.0f, 0.0f};                                       \
    __builtin_amdgcn_s_setprio(1);                                              \
    _Pragma("unroll")                                                           \
    for (int kt = 0; kt < 4; ++kt) {                                            \
        BFU B;                                                                  \
        B.u[0] = pk[2 * kt][0];     B.u[1] = pk[2 * kt][1];                     \
        B.u[2] = pk[2 * kt + 1][0]; B.u[3] = pk[2 * kt + 1][1];                 \
        bf16x8 A = *(const bf16x8*)(LDSW + (8 + kt) * 1024 + lb);               \
        if (kt & 1) a2B = __builtin_amdgcn_mfma_f32_16x16x32_bf16(A, B.v, a2B, 0, 0, 0); \
        else        a2A = __builtin_amdgcn_mfma_f32_16x16x32_bf16(A, B.v, a2A, 0, 0, 0); \
    }                                                                           \
    __builtin_amdgcn_s_setprio(0);                                              \
    f32x4 accd = a2A + a2B;                                                     \
    float dens = fmaxf(accd[0], 0.0f);                                          \
    BFU Bk0, Bk1;                                                               \
    Bk0.u[0] = pack2(accd[0], accd[1]);                                         \
    Bk0.u[1] = pack2(accd[2], accd[3]);                                         \
    Bk0.u[2] = pack2(E0, E1);                                                   \
    Bk0.u[3] = pack2(E2, E3);                                                   \
    Bk1.u[0] = pack2(G0, G1);                                                   \
    Bk1.u[1] = pack2(G2, G3);                                                   \
    Bk1.u[2] = pack2(G4, G5);                                                   \
    Bk1.u[3] = pack2(G6, G7);                                                   \
    f32x4 acc3[8];                                                              \
    __builtin_amdgcn_s_setprio(1);                                              \
    _Pragma("unroll")                                                           \
    for (int n = 0; n < 8; ++n) {                                               \
        f32x4 bi = *(const f32x4*)(ldsB3 + n * 16 + kg * 4);                    \
        bf16x8 w0 = *(const bf16x8*)(LDSW + (12 + n * 2 + 0) * 1024 + lb);      \
        bf16x8 w1 = *(const bf16x8*)(LDSW + (12 + n * 2 + 1) * 1024 + lb);      \
        acc3[n] = __builtin_amdgcn_mfma_f32_16x16x32_bf16(w0, Bk0.v, bi, 0, 0, 0);      \
        acc3[n] = __builtin_amdgcn_mfma_f32_16x16x32_bf16(w1, Bk1.v, acc3[n], 0, 0, 0); \
    }                                                                           \
    __builtin_amdgcn_s_setprio(0);                                              \
    unsigned int pk3[8][2];                                                     \
    _Pragma("unroll")                                                           \
    for (int n = 0; n < 8; ++n) {                                               \
        pk3[n][0] = pack2(fmaxf(acc3[n][0], 0.0f), fmaxf(acc3[n][1], 0.0f));    \
        pk3[n][1] = pack2(fmaxf(acc3[n][2], 0.0f), fmaxf(acc3[n][3], 0.0f));    \
    }                                                                           \
    f32x4 a4A = *(const f32x4*)(ldsB4 + kg * 4);                                \
    f32x4 a4B = {0.0f, 0.0f, 0.0f, 0.0f};                                       \
    __builtin_amdgcn_s_setprio(1);                                              \
    _Pragma("unroll")                                                           \
    for (int kt = 0; kt < 4; ++kt) {                                            \
        BFU B;                                                                  \
        B.u[0] = pk3[2 * kt][0];     B.u[1] = pk3[2 * kt][1];                   \
        B.u[2] = pk3[2 * kt + 1][0]; B.u[3] = pk3[2 * kt + 1][1];               \
        bf16x8 A = *(const bf16x8*)(LDSW + (28 + kt) * 1024 + lb);              \
        if (kt & 1) a4B = __builtin_amdgcn_mfma_f32_16x16x32_bf16(A, B.v, a4B, 0, 0, 0); \
        else        a4A = __builtin_amdgcn_mfma_f32_16x16x32_bf16(A, B.v, a4A, 0, 0, 0); \
    }                                                                           \
    __builtin_amdgcn_s_setprio(0);                                              \
    f32x4 acco = a4A + a4B;

// consume one corner slice (bf16x8 -> 8 f32 fma into fa/fb)
#define CONSUME(GV, W) {                                                        \
    BFU g; g.v = (GV);                                                          \
    float w_ = (W);                                                             \
    fa[0] = fmaf(w_, __uint_as_float(g.u[0] << 16),          fa[0]);            \
    fa[1] = fmaf(w_, __uint_as_float(g.u[0] & 0xffff0000u),  fa[1]);            \
    fa[2] = fmaf(w_, __uint_as_float(g.u[1] << 16),          fa[2]);            \
    fa[3] = fmaf(w_, __uint_as_float(g.u[1] & 0xffff0000u),  fa[3]);            \
    fb[0] = fmaf(w_, __uint_as_float(g.u[2] << 16),          fb[0]);            \
    fb[1] = fmaf(w_, __uint_as_float(g.u[2] & 0xffff0000u),  fb[1]);            \
    fb[2] = fmaf(w_, __uint_as_float(g.u[3] << 16),          fb[2]);            \
    fb[3] = fmaf(w_, __uint_as_float(g.u[3] & 0xffff0000u),  fb[3]);            \
}

// ---------------------------------------------------------------------------
// Dispatch 4: pipelined main kernel. bf16 L3-resident grid; iteration t
// consumes corner slices loaded during t-1, issues t+1's 8 x 16-B loads,
// then runs the MLP while they fly. Lane-local 16-B record decode.
// ---------------------------------------------------------------------------
__global__ __launch_bounds__(512)
void nerf_pipe(const __bf16* __restrict__ gb,
               const unsigned int* __restrict__ rec,
               const float* __restrict__ bd1,
               const float* __restrict__ bd2,
               const float* __restrict__ bc1,
               const float* __restrict__ bc2,
               const __bf16* __restrict__ wp,
               float* __restrict__ out,
               int ntiles)                          // 128-point tiles
{
    __shared__ __align__(16) char lds[32768 + 1152];
    float* ldsB1 = (float*)(lds + 32768);
    float* ldsB2 = ldsB1 + 128;
    float* ldsB3 = ldsB2 + 16;
    float* ldsB4 = ldsB3 + 128;

    const int tid = threadIdx.x;
    {
        const i32x4* src = (const i32x4*)wp;
        i32x4* dst = (i32x4*)lds;
        for (int i = tid; i < 2048; i += 512) dst[i] = src[i];
        if (tid < 128) ldsB1[tid] = bd1[tid];
        if (tid < 16)  ldsB2[tid] = bd2[tid];
        if (tid < 128) ldsB3[tid] = bc1[tid];
        if (tid < 16)  ldsB4[tid] = (tid < 3) ? bc2[tid] : 0.0f;
    }
    __syncthreads();

    const int lane = tid & 63;
    const int wid  = tid >> 6;
    const int c    = lane & 15;
    const int kg   = lane >> 4;
    const int lb   = lane * 16;

    const int per = (ntiles + gridDim.x - 1) / gridDim.x;
    int sb = blockIdx.x;
    if ((gridDim.x & 7) == 0)
        sb = (blockIdx.x & 7) * (gridDim.x >> 3) + (blockIdx.x >> 3);

    // ---- prologue ----------------------------------------------------------
    int t0 = sb * per;       if (t0 >= ntiles) t0 = ntiles - 1;
    int t1 = sb * per + 1;   if (t1 >= ntiles) t1 = ntiles - 1;
    i32x4 recA = ((const i32x4*)rec)[(size_t)t0 * 128 + wid * 16 + c];
    i32x4 recB = ((const i32x4*)rec)[(size_t)t1 * 128 + wid * 16 + c];

    bf16x8 g0, g1, g2, g3, g4, g5, g6, g7;
    float txc, tyc, tzc;
    {   // prep iter 0 from recA
        float px = (float)((unsigned)recA.x & 0xffffu) * (127.0f / 65535.0f);
        float py = (float)((unsigned)recA.x >> 16)     * (127.0f / 65535.0f);
        float pz = (float)((unsigned)recA.y & 0xffffu) * (127.0f / 65535.0f);
        int ix = (int)floorf(px); ix = ix < 0 ? 0 : (ix > 126 ? 126 : ix);
        int iy = (int)floorf(py); iy = iy < 0 ? 0 : (iy > 126 ? 126 : iy);
        int iz = (int)floorf(pz); iz = iz < 0 ? 0 : (iz > 126 ? 126 : iz);
        txc = px - (float)ix; tyc = py - (float)iy; tzc = pz - (float)iz;
        const __bf16* gp = gb + ((((size_t)ix << 14) + ((size_t)iy << 7) + iz) * 32 + kg * 8);
        g0 = *(const bf16x8*)(gp);
        g1 = *(const bf16x8*)(gp + 32);
        g2 = *(const bf16x8*)(gp + 4096);
        g3 = *(const bf16x8*)(gp + 4128);
        g4 = *(const bf16x8*)(gp + 524288);
        g5 = *(const bf16x8*)(gp + 524320);
        g6 = *(const bf16x8*)(gp + 528384);
        g7 = *(const bf16x8*)(gp + 528416);
    }

    for (int it = 0; it < per; ++it) {
        const int tile = sb * per + it;
        if (tile >= ntiles) break;

        // ---- consume current corner slices -> b0 frag ----------------------
        f32x4 fa = {0.0f, 0.0f, 0.0f, 0.0f};
        f32x4 fb = {0.0f, 0.0f, 0.0f, 0.0f};
        {
            float wx1 = txc, wx0 = 1.0f - txc;
            float wy1 = tyc, wy0 = 1.0f - tyc;
            float wz1 = tzc, wz0 = 1.0f - tzc;
            float wA = wx0 * wy0, wB = wx0 * wy1;
            float wC = wx1 * wy0, wD = wx1 * wy1;
            CONSUME(g0, wA * wz0)   // (0,0,0)
            CONSUME(g1, wA * wz1)   // (0,0,1)
            CONSUME(g2, wB * wz0)   // (0,1,0)
            CONSUME(g3, wB * wz1)   // (0,1,1)
            CONSUME(g4, wC * wz0)   // (1,0,0)
            CONSUME(g5, wC * wz1)   // (1,0,1)
            CONSUME(g6, wD * wz0)   // (1,1,0)
            CONSUME(g7, wD * wz1)   // (1,1,1)
        }
        BFU b0;
        b0.u[0] = pack2(fa[0], fa[1]); b0.u[1] = pack2(fa[2], fa[3]);
        b0.u[2] = pack2(fb[0], fb[1]); b0.u[3] = pack2(fb[2], fb[3]);

        // ---- current dirs / output index (lane-local decode) ---------------
        float dxv = fmaf((float)((unsigned)recA.y >> 16),     2.0f / 65535.0f, -1.0f);
        float dyv = fmaf((float)((unsigned)recA.z & 0xffffu), 2.0f / 65535.0f, -1.0f);
        float dzv = fmaf((float)((unsigned)recA.z >> 16),     2.0f / 65535.0f, -1.0f);
        int   pv  = recA.w;

        // ---- prep NEXT iteration from recB: issue 8 corner loads -----------
        {
            float px = (float)((unsigned)recB.x & 0xffffu) * (127.0f / 65535.0f);
            float py = (float)((unsigned)recB.x >> 16)     * (127.0f / 65535.0f);
            float pz = (float)((unsigned)recB.y & 0xffffu) * (127.0f / 65535.0f);
            int ix = (int)floorf(px); ix = ix < 0 ? 0 : (ix > 126 ? 126 : ix);
            int iy = (int)floorf(py); iy = iy < 0 ? 0 : (iy > 126 ? 126 : iy);
            int iz = (int)floorf(pz); iz = iz < 0 ? 0 : (iz > 126 ? 126 : iz);
            txc = px - (float)ix; tyc = py - (float)iy; tzc = pz - (float)iz;
            const __bf16* gp = gb + ((((size_t)ix << 14) + ((size_t)iy << 7) + iz) * 32 + kg * 8);
            g0 = *(const bf16x8*)(gp);
            g1 = *(const bf16x8*)(gp + 32);
            g2 = *(const bf16x8*)(gp + 4096);
            g3 = *(const bf16x8*)(gp + 4128);
            g4 = *(const bf16x8*)(gp + 524288);
            g5 = *(const bf16x8*)(gp + 524320);
            g6 = *(const bf16x8*)(gp + 528384);
            g7 = *(const bf16x8*)(gp + 528416);
        }
        // rotate records: recA <- recB, load new recB (t+2)
        recA = recB;
        {
            int t2 = tile + 2; if (t2 >= ntiles) t2 = ntiles - 1;
            recB = ((const i32x4*)rec)[(size_t)t2 * 128 + wid * 16 + c];
        }

        // ---- MLP (corner loads above retire underneath) --------------------
        NERF_MLP_BODY(lds + 0)

        if (lane < 16) {
            f32x4 o;
            o[0] = 1.0f / (1.0f + __expf(-acco[0]));
            o[1] = 1.0f / (1.0f + __expf(-acco[1]));
            o[2] = 1.0f / (1.0f + __expf(-acco[2]));
            o[3] = dens;
            ((f32x4*)out)[pv] = o;
        }
    }
}

// ---------------------------------------------------------------------------
// Fallback (no workspace): unsorted fp32-gather kernel.
// ---------------------------------------------------------------------------
__global__ void pack_weights_fb(const float* __restrict__ wd1,
                                const float* __restrict__ wd2,
                                const float* __restrict__ wc1,
                                const float* __restrict__ wc2,
                                __bf16* __restrict__ wp)
{
    int t = blockIdx.x * 256 + threadIdx.x;
    int frag = t >> 6;
    int lane = t & 63;
    int kg = lane >> 4;
    int c  = lane & 15;
    for (int j = 0; j < 8; ++j) {
        float v;
        if (frag < 8) {
            int k = kg * 8 + j;
            v = wd1[k * 128 + frag * 16 + c];
        } else if (frag < 12) {
            int kt = frag - 8;
            int row = 32 * kt + 16 * (j >> 2) + 4 * kg + (j & 3);
            v = wd2[row * 16 + c];
        } else if (frag < 28) {
            int f = frag - 12;
            int f3 = f >> 1, kt3 = f & 1;
            int row;
            if (kt3 == 0) row = (j < 4) ? (4 * kg + j) : (16 + 4 * kg + (j - 4));
            else          row = 32 + 8 * kg + j;
            v = (row < 43) ? wc1[row * 128 + f3 * 16 + c] : 0.0f;
        } else {
            int kt = frag - 28;
            int row = 32 * kt + 16 * (j >> 2) + 4 * kg + (j & 3);
            v = (c < 3) ? wc2[row * 3 + c] : 0.0f;
        }
        wp[frag * 512 + lane * 8 + j] = (__bf16)v;
    }
}

__global__ __launch_bounds__(512)
void nerf_plain(const float* __restrict__ coords,
                const float* __restrict__ ray_d,
                const float* __restrict__ grid,
                const float* __restrict__ bd1,
                const float* __restrict__ bd2,
                const float* __restrict__ bc1,
                const float* __restrict__ bc2,
                const __bf16* __restrict__ wp,
                float* __restrict__ out,
                int ntiles)
{
    __shared__ __align__(16) char lds[32768 + 1152];
    float* ldsB1 = (float*)(lds + 32768);
    float* ldsB2 = ldsB1 + 128;
    float* ldsB3 = ldsB2 + 16;
    float* ldsB4 = ldsB3 + 128;

    const int tid = threadIdx.x;
    {
        const i32x4* src = (const i32x4*)wp;
        i32x4* dst = (i32x4*)lds;
        for (int i = tid; i < 2048; i += 512) dst[i] = src[i];
        if (tid < 128) ldsB1[tid] = bd1[tid];
        if (tid < 16)  ldsB2[tid] = bd2[tid];
        if (tid < 128) ldsB3[tid] = bc1[tid];
        if (tid < 16)  ldsB4[tid] = (tid < 3) ? bc2[tid] : 0.0f;
    }
    __syncthreads();

    const int lane = tid & 63;
    const int wid  = tid >> 6;
    const int c    = lane & 15;
    const int kg   = lane >> 4;
    const int lb   = lane * 16;

    for (int tile = blockIdx.x; tile < ntiles; tile += gridDim.x) {
        int pw = tile * 128 + wid * 16;
        float cval = (lane < 48) ? coords[(size_t)pw * 3 + lane] : 0.0f;
        float rval = (lane < 48) ? ray_d[(size_t)pw * 3 + lane] : 0.0f;
        float px  = __shfl(cval, 3 * c + 0) * 127.0f;
        float py  = __shfl(cval, 3 * c + 1) * 127.0f;
        float pz  = __shfl(cval, 3 * c + 2) * 127.0f;
        float dxv = __shfl(rval, 3 * c + 0);
        float dyv = __shfl(rval, 3 * c + 1);
        float dzv = __shfl(rval, 3 * c + 2);
        int pv = pw + c;

        int ix = (int)floorf(px); ix = ix < 0 ? 0 : (ix > 126 ? 126 : ix);
        int iy = (int)floorf(py); iy = iy < 0 ? 0 : (iy > 126 ? 126 : iy);
        int iz = (int)floorf(pz); iz = iz < 0 ? 0 : (iz > 126 ? 126 : iz);
        float tx = px - (float)ix;
        float ty = py - (float)iy;
        float tz = pz - (float)iz;

        f32x4 fa = {0.0f, 0.0f, 0.0f, 0.0f};
        f32x4 fb = {0.0f, 0.0f, 0.0f, 0.0f};
#pragma unroll
        for (int cc = 0; cc < 8; ++cc) {
            int ddx = (cc >> 2) & 1, ddy = (cc >> 1) & 1, ddz = cc & 1;
            float w = (ddx ? tx : 1.0f - tx) *
                      (ddy ? ty : 1.0f - ty) *
                      (ddz ? tz : 1.0f - tz);
            int idx = ((ix + ddx) << 14) + ((iy + ddy) << 7) + (iz + ddz);
            const f32x4* g = (const f32x4*)(grid + (size_t)idx * 32 + kg * 8);
            f32x4 v0 = g[0], v1 = g[1];
#pragma unroll
            for (int e = 0; e < 4; ++e) {
                fa[e] = fmaf(w, v0[e], fa[e]);
                fb[e] = fmaf(w, v1[e], fb[e]);
            }
        }
        BFU b0;
        b0.u[0] = pack2(fa[0], fa[1]); b0.u[1] = pack2(fa[2], fa[3]);
        b0.u[2] = pack2(fb[0], fb[1]); b0.u[3] = pack2(fb[2], fb[3]);

        NERF_MLP_BODY(lds + 0)

        if (lane < 16) {
            f32x4 o;
            o[0] = 1.0f / (1.0f + __expf(-acco[0]));
            o[1] = 1.0f / (1.0f + __expf(-acco[1]));
            o[2] = 1.0f / (1.0f + __expf(-acco[2]));
            o[3] = dens;
            ((f32x4*)out)[pv] = o;
        }
    }
}

extern "C" void kernel_launch(void* const* d_in, const int* in_sizes, int n_in,
                              void* d_out, int out_size, void* d_ws, size_t ws_size,
                              hipStream_t stream) {
    const float* coords = (const float*)d_in[0];
    const float* ray_d  = (const float*)d_in[1];
    const float* grid   = (const float*)d_in[2];
    const float* wd1    = (const float*)d_in[3];
    const float* bd1    = (const float*)d_in[4];
    const float* wd2    = (const float*)d_in[5];
    const float* bd2    = (const float*)d_in[6];
    const float* wc1    = (const float*)d_in[7];
    const float* bc1    = (const float*)d_in[8];
    const float* wc2    = (const float*)d_in[9];
    const float* bc2    = (const float*)d_in[10];
    float* out = (float*)d_out;

    int N = in_sizes[0] / 3;
    int gridElems = in_sizes[2];
    int ntiles = N >> 7;

    char* ws = (char*)d_ws;
    __bf16* wp = (__bf16*)(ws + WS_WP);

    bool sortable = (N % (HB * 128)) == 0;

    if (ws_size >= WS_FULL && sortable) {
        unsigned int* mat   = (unsigned int*)(ws + WS_MAT);
        unsigned int* total = (unsigned int*)(ws + WS_TOT);
        unsigned int* rec   = (unsigned int*)(ws + WS_REC);
        __bf16* gb = (__bf16*)(ws + WS_GB);
        int ppb = N / HB;
        int n8 = gridElems / 8;

        pack_hist<<<8 + HB, 256, 0, stream>>>(wd1, wd2, wc1, wc2, wp,
                                              coords, mat, ppb);
        col_scan<<<NBUCKET / 4, 256, 0, stream>>>(mat, total);
        scatter_conv<<<HB + 2048, 256, 0, stream>>>(coords, ray_d, mat, total,
                                                    rec, ppb, grid, gb, n8);
        int blocks = ntiles < 2048 ? ntiles : 2048;
        nerf_pipe<<<blocks, 512, 0, stream>>>(gb, rec,
                                              bd1, bd2, bc1, bc2, wp, out, ntiles);
    } else {
        pack_weights_fb<<<8, 256, 0, stream>>>(wd1, wd2, wc1, wc2, wp);
        int blocks = ntiles < 2048 ? ntiles : 2048;
        nerf_plain<<<blocks, 512, 0, stream>>>(coords, ray_d, grid,
                                               bd1, bd2, bc1, bc2,
                                               wp, out, ntiles);
    }
}